// Round 10
// baseline (95.549 us; speedup 1.0000x reference)
//
#include <hip/hip_runtime.h>

// out[b,e,j] = bias[j] + sum_k weight[k,j] * y[b, e+k-7, j]
// y[b,e',j]  = sum_{i<=j} x[b,e',i] * dv^(j-i)   (decayed prefix scan over features)
// dv = clip(decay_value[1], 0.9, 1.0); y rows with e' < 0 are zero.
//
// R10 = R9 (best: 91.08) + three micro-fixes:
//  1. balanced phase-1: row r -> wave (r&3), 4-lane segment group (r>>2);
//     rows/wave {10,10,10,9} instead of {16,16,7,0}; shuffle hops distance 1/2.
//  2. XCD swizzle: b = blockIdx&7, tile = blockIdx>>3 -> all tiles of one b on
//     one XCD (round-robin %8 mapping); halo rows shared tile<->tile+1 hit L2.
//  3. staging bounds-check hoisted to a block-uniform branch (tile 0 only).

#define B_     8
#define E_     2048
#define DIM_   512
#define K_     8
#define TILE_E 32
#define NROWS  (TILE_E + K_ - 1)     // 39
#define LSTR   516                   // floats; 2064 B row stride (16B aligned)
#define NF4    (NROWS * (DIM_ / 4))  // 4992 float4 staging chunks

__global__ __launch_bounds__(256) void krl_t(
    const float* __restrict__ x,
    const float* __restrict__ weight,
    const float* __restrict__ bias,
    const float* __restrict__ decay,
    float* __restrict__ out)
{
    __shared__ float yls[NROWS * LSTR];   // 80,496 B -> 2 blocks/CU

    const int t    = threadIdx.x;
    const int b    = blockIdx.x & 7;      // XCD-affine: batch <-> XCD
    const int tile = blockIdx.x >> 3;
    const int e0   = tile * TILE_E;

    // ---- Phase 0: stage 39 x-rows into padded LDS, coalesced float4 ----
    const int ebase = e0 - (K_ - 1);
    if (ebase >= 0) {                     // common path: no per-iter guard
        const float* xb = x + ((size_t)b * E_ + ebase) * DIM_;
        for (int i = t; i < NF4; i += 256) {
            const int r = i >> 7, f4 = i & 127;
            *(float4*)(&yls[r * LSTR + f4 * 4]) =
                *(const float4*)(xb + (size_t)r * DIM_ + f4 * 4);
        }
    } else {                              // tile 0 only
        for (int i = t; i < NF4; i += 256) {
            const int r = i >> 7, f4 = i & 127;
            const int eg = ebase + r;
            float4 v = make_float4(0.f, 0.f, 0.f, 0.f);
            if (eg >= 0)
                v = *(const float4*)(x + ((size_t)b * E_ + eg) * DIM_ + f4 * 4);
            *(float4*)(&yls[r * LSTR + f4 * 4]) = v;
        }
    }

    float dv = decay[1];
    dv = fminf(fmaxf(dv, 0.9f), 1.0f);
    const float d1 = dv, d2 = dv * dv, d3 = d2 * dv, d4 = d2 * d2;
    float d128 = d4;                      // dv^4 squared 5x = dv^128
    d128 *= d128; d128 *= d128; d128 *= d128; d128 *= d128; d128 *= d128;
    const float d256 = d128 * d128;

    __syncthreads();

    // ---- Phase 1: transposed two-level decayed scan (in-place in LDS) ----
    // row r handled by wave (r&3), lanes 4*(r>>2)..4*(r>>2)+3 (seg = lane&3).
    const int lane = t & 63, wave = t >> 6;
    const int grp = lane >> 2, seg = lane & 3;
    const int row = grp * 4 + wave;       // waves get {10,10,10,9} rows
    if (row < NROWS) {
        float* sp = &yls[row * LSTR + seg * 128];

        // pass 1: segment-end Horner  E = sum_m x[m] * dv^(127-m)
        float E = 0.f;
        #pragma unroll 8
        for (int q = 0; q < 32; ++q) {
            const float4 v = *(const float4*)(sp + 4 * q);
            const float p = fmaf(d3, v.x, fmaf(d2, v.y, fmaf(d1, v.z, v.w)));
            E = fmaf(d4, E, p);
        }

        // level 2: carry across the row's 4 segments (hops of 1 and 2 lanes)
        float S = E;
        float u1 = __shfl_up(S, 1, 64); if (seg >= 1) S = fmaf(d128, u1, S);
        float u2 = __shfl_up(S, 2, 64); if (seg >= 2) S = fmaf(d256, u2, S);
        float C  = __shfl_up(S, 1, 64); if (seg == 0) C = 0.f;  // y[seg*128-1]

        // pass 2: carry-propagating scan, 1 chained FMA per 4 elements
        float prev = C;
        #pragma unroll 8
        for (int q = 0; q < 32; ++q) {
            const float4 v = *(const float4*)(sp + 4 * q);
            const float p01   = fmaf(d1, v.x, v.y);
            const float p012  = fmaf(d1, p01, v.z);
            const float p0123 = fmaf(d1, p012, v.w);
            float4 yv;
            yv.x = fmaf(d1, prev, v.x);
            yv.y = fmaf(d2, prev, p01);
            yv.z = fmaf(d3, prev, p012);
            yv.w = fmaf(d4, prev, p0123);
            prev = yv.w;
            *(float4*)(sp + 4 * q) = yv;
        }
    }

    // Phase-2 operands issued before the barrier (latency hides under it).
    const int j  = t & 127, h = t >> 7;
    const int jf = j * 4;
    float4 w[K_];
    #pragma unroll
    for (int k = 0; k < K_; ++k) w[k] = *(const float4*)(weight + k * DIM_ + jf);
    const float4 bi = *(const float4*)(bias + jf);

    __syncthreads();

    // ---- Phase 2: rolling-window conv; each y row read ONCE from LDS ----
    const int te0 = h * 16;               // h=0: outputs 0..15, h=1: 16..31
    float4 win[K_];
    #pragma unroll
    for (int k = 0; k < 7; ++k)
        win[k] = *(const float4*)(&yls[(te0 + k) * LSTR + jf]);

    #pragma unroll
    for (int i = 0; i < 16; ++i) {
        const int te = te0 + i;
        win[7] = *(const float4*)(&yls[(te + 7) * LSTR + jf]);
        float4 acc = bi;
        #pragma unroll
        for (int k = 0; k < K_; ++k) {
            acc.x = fmaf(w[k].x, win[k].x, acc.x);
            acc.y = fmaf(w[k].y, win[k].y, acc.y);
            acc.z = fmaf(w[k].z, win[k].z, acc.z);
            acc.w = fmaf(w[k].w, win[k].w, acc.w);
        }
        *(float4*)(out + ((size_t)b * E_ + e0 + te) * DIM_ + jf) = acc;
        #pragma unroll
        for (int k = 0; k < 7; ++k) win[k] = win[k + 1];   // renamed, free
    }
}

extern "C" void kernel_launch(void* const* d_in, const int* in_sizes, int n_in,
                              void* d_out, int out_size, void* d_ws, size_t ws_size,
                              hipStream_t stream) {
    const float* x      = (const float*)d_in[0];
    const float* weight = (const float*)d_in[1];
    const float* bias   = (const float*)d_in[2];
    const float* decay  = (const float*)d_in[3];
    float* out = (float*)d_out;

    // 512 blocks, 1-D grid; kernel derives (b, tile) XCD-affinely.
    krl_t<<<dim3(B_ * (E_ / TILE_E)), dim3(256), 0, stream>>>(
        x, weight, bias, decay, out);
}